// Round 4
// baseline (2590.138 us; speedup 1.0000x reference)
//
#include <hip/hip_runtime.h>
#include <math.h>

#define HD 128
#define NBR 8
#define LSTEPS 64
#define TILE_B 32
#define HT_PAD 36
#define PART_PAD 33

// ws offsets (floats)
#define QB_OFF   0          // [cls][cg][hid][q] = 0.5*g_emb@w_ih^T + bias   (NC*512)
#define WHH_OFF  524288     // [k][cg][hid][q]  = w_hh[(q*128+2cg+hid)][k]   (65536)
#define PP_OFF   589824     // [br][cg][hid][q] = 0.5*w_emb@w_ih^T           (4096)
#define B2_OFF   593920     // [cg][hid][q]     = b_ih+b_hh                  (512)
// total 594432 floats = 2.38 MB

__device__ __forceinline__ float fsig(float x) {
  return __builtin_amdgcn_rcpf(1.f + __expf(-x));
}
__device__ __forceinline__ float ftanh(float x) {
  return 1.f - 2.f * __builtin_amdgcn_rcpf(1.f + __expf(2.f * x));
}

__global__ __launch_bounds__(256) void setup_kernel(
    const float* __restrict__ g_emb, const float* __restrict__ w_emb,
    const float* __restrict__ w_ih,  const float* __restrict__ w_hh,
    const float* __restrict__ b_ih,  const float* __restrict__ b_hh,
    float* __restrict__ ws, int NC)
{
  int tid = blockIdx.x * 256 + threadIdx.x;
  int qbN = NC * 512;
  if (tid < qbN) {
    int cls = tid >> 9, col = tid & 511;
    int cg = col >> 3, hid = (col >> 2) & 1, q = col & 3;
    int row = q*HD + 2*cg + hid;
    const float* er = g_emb + (size_t)cls * HD;
    const float* wr = w_ih + (size_t)row * HD;
    float s = 0.f;
    for (int k = 0; k < HD; ++k) s = fmaf(er[k], wr[k], s);
    ws[QB_OFF + tid] = 0.5f * s + b_ih[row] + b_hh[row];
    return;
  }
  int t2 = tid - qbN;
  if (t2 < 65536) {
    int k = t2 >> 9, col = t2 & 511;
    int cg = col >> 3, hid = (col >> 2) & 1, q = col & 3;
    ws[WHH_OFF + t2] = w_hh[(q*HD + 2*cg + hid)*HD + k];
    return;
  }
  int t3 = t2 - 65536;
  if (t3 < 4096) {
    int br = t3 >> 9, col = t3 & 511;
    int cg = col >> 3, hid = (col >> 2) & 1, q = col & 3;
    int row = q*HD + 2*cg + hid;
    const float* er = w_emb + br*HD;
    const float* wr = w_ih + (size_t)row * HD;
    float s = 0.f;
    for (int k = 0; k < HD; ++k) s = fmaf(er[k], wr[k], s);
    ws[PP_OFF + t3] = 0.5f * s;
    return;
  }
  int t4 = t3 - 4096;
  if (t4 < 512) {
    int cg = t4 >> 3, hid = (t4 >> 2) & 1, q = t4 & 3;
    int row = q*HD + 2*cg + hid;
    ws[B2_OFF + t4] = b_ih[row] + b_hh[row];
  }
}

// 128 threads: lane cg = tid&63 (gate-col group: hidden pair 2cg,2cg+1 x 4 quads),
// bg = tid>>6 (batch half). Thread tile: 16 batches x 8 gate-cols.
__global__ __launch_bounds__(128, 1) void ctrl_kernel(
    const int* __restrict__ class_ids,
    const float* __restrict__ gumbel_u,
    const float* __restrict__ w_soft,
    const float* __restrict__ ws,
    float* __restrict__ out,
    int Btot)
{
  __shared__ float hT[HD * HT_PAD];          // 18432 B  h^T [hid][b]
  __shared__ float ws_l[NBR * HD];           // 4096 B
  __shared__ float part_l[TILE_B * PART_PAD];// 4224 B
  __shared__ int   br_l[TILE_B];             // 128 B   -> ~27 KB/block

  const int tid = threadIdx.x;
  const int cg  = tid & 63;
  const int bg  = tid >> 6;
  const int b0  = blockIdx.x * TILE_B;
  const size_t BL = (size_t)Btot * LSTEPS;

  for (int i = tid; i < NBR*HD; i += 128) ws_l[i] = w_soft[i];

  const float* __restrict__ wkbase = ws + WHH_OFF + cg*8;
  const float* __restrict__ qb     = ws + QB_OFF + cg*8;
  const float* __restrict__ ppb    = ws + PP_OFF + cg*8;

  float bias8[8];
  {
    const float* bp = ws + B2_OFF + cg*8;
    float4 bA = *(const float4*)(bp);
    float4 bB = *(const float4*)(bp + 4);
    bias8[0]=bA.x; bias8[1]=bA.y; bias8[2]=bA.z; bias8[3]=bA.w;
    bias8[4]=bB.x; bias8[5]=bB.y; bias8[6]=bB.z; bias8[7]=bB.w;
  }

  int cidq[16];
  #pragma unroll
  for (int j = 0; j < 16; ++j)
    cidq[j] = class_ids[b0 + bg*16 + j] << 9;   // *512

  float cc[16][2];
  #pragma unroll
  for (int j = 0; j < 16; ++j) { cc[j][0] = 0.f; cc[j][1] = 0.f; }

  const int s_lb = tid & 31;       // logit/sampling batch lane
  const int s_ch = tid >> 5;       // k-chunk 0..3

  for (int t = 0; t < LSTEPS; ++t) {
    // prefetch gumbel u (overlaps GEMM)
    float4 ua = make_float4(0,0,0,0), ub = make_float4(0,0,0,0);
    if (tid < TILE_B) {
      const float* up = gumbel_u + ((size_t)t * Btot + (b0 + tid)) * NBR;
      ua = *(const float4*)up;
      ub = *(const float4*)(up + 4);
    }

    // ---- GEMM: acc[j][hid*4+q] = sum_k h[k][bj] * whh[k][col] ----
    float acc[16][8];
    #pragma unroll
    for (int j = 0; j < 16; ++j)
      #pragma unroll
      for (int g = 0; g < 8; ++g) acc[j][g] = 0.f;

    if (t > 0) {
      const float* wk = wkbase;
      const float* hr = &hT[bg*16];
      #pragma unroll 2
      for (int k = 0; k < HD; ++k) {
        float4 w0 = *(const float4*)(wk);
        float4 w1 = *(const float4*)(wk + 4);
        wk += 512;
        float4 h0 = *(const float4*)(hr);
        float4 h1 = *(const float4*)(hr + 4);
        float4 h2 = *(const float4*)(hr + 8);
        float4 h3 = *(const float4*)(hr + 12);
        hr += HT_PAD;
        #define FMAJ(j, hv) \
          acc[j][0]=fmaf(hv,w0.x,acc[j][0]); acc[j][1]=fmaf(hv,w0.y,acc[j][1]); \
          acc[j][2]=fmaf(hv,w0.z,acc[j][2]); acc[j][3]=fmaf(hv,w0.w,acc[j][3]); \
          acc[j][4]=fmaf(hv,w1.x,acc[j][4]); acc[j][5]=fmaf(hv,w1.y,acc[j][5]); \
          acc[j][6]=fmaf(hv,w1.z,acc[j][6]); acc[j][7]=fmaf(hv,w1.w,acc[j][7]);
        FMAJ(0,  h0.x) FMAJ(1,  h0.y) FMAJ(2,  h0.z) FMAJ(3,  h0.w)
        FMAJ(4,  h1.x) FMAJ(5,  h1.y) FMAJ(6,  h1.z) FMAJ(7,  h1.w)
        FMAJ(8,  h2.x) FMAJ(9,  h2.y) FMAJ(10, h2.z) FMAJ(11, h2.w)
        FMAJ(12, h3.x) FMAJ(13, h3.y) FMAJ(14, h3.z) FMAJ(15, h3.w)
        #undef FMAJ
      }
    }
    __syncthreads();   // (A) hT reads done; safe to overwrite

    // ---- pointwise LSTM; writes new h into hT ----
    #pragma unroll
    for (int j = 0; j < 16; ++j) {
      int jb = bg*16 + j;
      const float* qrow = qb + cidq[j];
      float4 qv0 = *(const float4*)(qrow);
      float4 qv1 = *(const float4*)(qrow + 4);
      float4 pv0, pv1;
      if (t == 0) {
        pv0.x = qv0.x - bias8[0]; pv0.y = qv0.y - bias8[1];
        pv0.z = qv0.z - bias8[2]; pv0.w = qv0.w - bias8[3];
        pv1.x = qv1.x - bias8[4]; pv1.y = qv1.y - bias8[5];
        pv1.z = qv1.z - bias8[6]; pv1.w = qv1.w - bias8[7];
      } else {
        const float* prow = ppb + (br_l[jb] << 9);
        pv0 = *(const float4*)(prow);
        pv1 = *(const float4*)(prow + 4);
      }
      // hid 0
      float gi = acc[j][0] + qv0.x + pv0.x;
      float gf = acc[j][1] + qv0.y + pv0.y;
      float gc = acc[j][2] + qv0.z + pv0.z;
      float go = acc[j][3] + qv0.w + pv0.w;
      float c0 = fsig(gf)*cc[j][0] + fsig(gi)*ftanh(gc);
      cc[j][0] = c0;
      hT[(2*cg)*HT_PAD + jb] = fsig(go)*ftanh(c0);
      // hid 1
      gi = acc[j][4] + qv1.x + pv1.x;
      gf = acc[j][5] + qv1.y + pv1.y;
      gc = acc[j][6] + qv1.z + pv1.z;
      go = acc[j][7] + qv1.w + pv1.w;
      float c1 = fsig(gf)*cc[j][1] + fsig(gi)*ftanh(gc);
      cc[j][1] = c1;
      hT[(2*cg+1)*HT_PAD + jb] = fsig(go)*ftanh(c1);
    }
    __syncthreads();   // (B) new h visible

    // ---- logit partials: thread (s_lb, s_ch), 32-k chunk ----
    {
      const float* hcol = &hT[(s_ch*32)*HT_PAD + s_lb];
      float part[8];
      #pragma unroll
      for (int nb = 0; nb < 8; ++nb) part[nb] = 0.f;
      #pragma unroll
      for (int ii = 0; ii < 32; ii += 4) {
        float hv0 = hcol[(ii+0)*HT_PAD];
        float hv1 = hcol[(ii+1)*HT_PAD];
        float hv2 = hcol[(ii+2)*HT_PAD];
        float hv3 = hcol[(ii+3)*HT_PAD];
        #pragma unroll
        for (int nb = 0; nb < 8; ++nb) {
          float4 wv = *(const float4*)(&ws_l[nb*HD + s_ch*32 + ii]);
          part[nb] = fmaf(hv0, wv.x, part[nb]);
          part[nb] = fmaf(hv1, wv.y, part[nb]);
          part[nb] = fmaf(hv2, wv.z, part[nb]);
          part[nb] = fmaf(hv3, wv.w, part[nb]);
        }
      }
      #pragma unroll
      for (int nb = 0; nb < 8; ++nb)
        part_l[s_lb*PART_PAD + nb*4 + s_ch] = part[nb];
    }
    __syncthreads();   // (C)

    // ---- sampling: one thread per batch row ----
    if (tid < TILE_B) {
      int lb = tid;
      float lg[8];
      #pragma unroll
      for (int nb = 0; nb < 8; ++nb) {
        const float* pr = &part_l[lb*PART_PAD + nb*4];
        float s = (pr[0] + pr[1]) + (pr[2] + pr[3]);
        lg[nb] = 2.5f * ftanh(s * 0.2f);
      }
      float uv[8] = {ua.x,ua.y,ua.z,ua.w,ub.x,ub.y,ub.z,ub.w};
      int br = 0; float best;
      {
        float uc = fminf(fmaxf(uv[0], 1e-8f), 0.99999999f);
        best = lg[0] - __logf(-__logf(uc));
      }
      #pragma unroll
      for (int nb = 1; nb < 8; ++nb) {
        float uc = fminf(fmaxf(uv[nb], 1e-8f), 0.99999999f);
        float y = lg[nb] - __logf(-__logf(uc));
        if (y > best) { best = y; br = nb; }
      }
      float m = lg[0];
      #pragma unroll
      for (int nb = 1; nb < 8; ++nb) m = fmaxf(m, lg[nb]);
      float se = 0.f;
      #pragma unroll
      for (int nb = 0; nb < 8; ++nb) se += __expf(lg[nb] - m);
      float lse = __logf(se);
      float lp = (lg[br] - m) - lse;
      float ent = 0.f;
      #pragma unroll
      for (int nb = 0; nb < 8; ++nb) {
        float lpi = (lg[nb] - m) - lse;
        ent -= __expf(lpi) * lpi;
      }
      size_t row = (size_t)(b0 + lb) * LSTEPS + t;
      out[row]        = (float)br;
      out[BL + row]   = lp;
      out[2*BL + row] = ent;
      out[3*BL + row] = __expf(lp);
      br_l[lb] = br;
    }
    __syncthreads();   // (E) br_l visible for next step
  }
}

extern "C" void kernel_launch(void* const* d_in, const int* in_sizes, int n_in,
                              void* d_out, int out_size, void* d_ws, size_t ws_size,
                              hipStream_t stream) {
  const int*   class_ids = (const int*)d_in[0];
  const float* gumbel_u  = (const float*)d_in[1];
  const float* g_emb     = (const float*)d_in[2];
  const float* w_emb     = (const float*)d_in[3];
  const float* w_soft    = (const float*)d_in[4];
  const float* w_ih      = (const float*)d_in[5];
  const float* w_hh      = (const float*)d_in[6];
  const float* b_ih      = (const float*)d_in[7];
  const float* b_hh      = (const float*)d_in[8];
  float* out = (float*)d_out;
  float* ws  = (float*)d_ws;
  int B  = in_sizes[0];
  int NC = in_sizes[2] / HD;

  int setup_items = NC*512 + 65536 + 4096 + 512;
  int setup_grid  = (setup_items + 255) / 256;
  hipLaunchKernelGGL(setup_kernel, dim3(setup_grid), dim3(256), 0, stream,
                     g_emb, w_emb, w_ih, w_hh, b_ih, b_hh, ws, NC);
  hipLaunchKernelGGL(ctrl_kernel, dim3(B / TILE_B), dim3(128), 0, stream,
                     class_ids, gumbel_u, w_soft, ws, out, B);
}